// Round 1
// baseline (73.774 us; speedup 1.0000x reference)
//
#include <hip/hip_runtime.h>
#include <math.h>

#define NB 2048
#define ND 784
#define NK 128
#define BM 32
#define DSPLIT 4
#define DPB (ND / DSPLIT)   // 196, multiple of 4
#define KD (ND * NK)        // 100352

// ws layout (floats):
//   ta[KD] | tb[KD] | tc[KD] | logw[NK] | part[DSPLIT*NB*NK]
// total = 3*100352 + 128 + 4*2048*128 = 1,349,760 floats = 5.15 MB

__global__ __launch_bounds__(256) void k_tables(
    const float* __restrict__ w, const float* __restrict__ mu,
    const float* __restrict__ cov, float* __restrict__ ws) {
  int idx = blockIdx.x * 256 + threadIdx.x;
  float* ta = ws;
  float* tb = ws + KD;
  float* tc = ws + 2 * KD;
  float* lw = ws + 3 * KD;
  if (idx < KD) {
    int k = idx & (NK - 1);   // table layout [d][k]
    int d = idx >> 7;
    float c = cov[k * ND + d];
    float m = mu[k * ND + d];
    float inv2 = 0.5f / c;
    ta[idx] = -inv2;
    tb[idx] = m / c;
    tc[idx] = -m * m * inv2 - 0.5f * logf(c);
  }
  if (idx < NK) lw[idx] = logf(w[idx]);
}

// One block = 32 rows x 128 centers x 196 dims (a D-quarter).
// Thread (tx=tid&31, ty=tid>>5): 4 rows {ty, ty+8, ty+16, ty+24} x 4 k {4tx..4tx+3}.
__global__ __launch_bounds__(256) void k_main(
    const float* __restrict__ data, const float* __restrict__ mask,
    float* __restrict__ ws) {
  const float* ta = ws;
  const float* tb = ws + KD;
  const float* tc = ws + 2 * KD;
  float* part = ws + 3 * KD + NK;

  int blk = blockIdx.x;
  int mt  = blk >> 2;       // / DSPLIT
  int dsp = blk & 3;        // % DSPLIT
  int r0 = mt * BM;
  int d0 = dsp * DPB;
  int tx = threadIdx.x & 31;
  int ty = threadIdx.x >> 5;
  int kb = tx << 2;

  float acc[4][4];
#pragma unroll
  for (int i = 0; i < 4; i++)
#pragma unroll
    for (int j = 0; j < 4; j++) acc[i][j] = 0.f;

  for (int dg = 0; dg < DPB; dg += 4) {
    int d = d0 + dg;
    float4 A[4], Bv[4], Cv[4];
#pragma unroll
    for (int dd = 0; dd < 4; dd++) {
      A[dd]  = *(const float4*)(ta + (size_t)(d + dd) * NK + kb);
      Bv[dd] = *(const float4*)(tb + (size_t)(d + dd) * NK + kb);
      Cv[dd] = *(const float4*)(tc + (size_t)(d + dd) * NK + kb);
    }
#pragma unroll
    for (int i = 0; i < 4; i++) {
      int r = r0 + ty + (i << 3);
      float4 x = *(const float4*)(data + (size_t)r * ND + d);
      float4 m = *(const float4*)(mask + (size_t)r * ND + d);
      float xs[4] = {x.x, x.y, x.z, x.w};
      float ms[4] = {m.x, m.y, m.z, m.w};
#pragma unroll
      for (int dd = 0; dd < 4; dd++) {
        float m0 = ms[dd];
        float m1 = m0 * xs[dd];
        float m2 = m1 * xs[dd];
        float4 a = A[dd], b = Bv[dd], c = Cv[dd];
        acc[i][0] = fmaf(m2, a.x, fmaf(m1, b.x, fmaf(m0, c.x, acc[i][0])));
        acc[i][1] = fmaf(m2, a.y, fmaf(m1, b.y, fmaf(m0, c.y, acc[i][1])));
        acc[i][2] = fmaf(m2, a.z, fmaf(m1, b.z, fmaf(m0, c.z, acc[i][2])));
        acc[i][3] = fmaf(m2, a.w, fmaf(m1, b.w, fmaf(m0, c.w, acc[i][3])));
      }
    }
  }

#pragma unroll
  for (int i = 0; i < 4; i++) {
    int r = r0 + ty + (i << 3);
    float4 v = make_float4(acc[i][0], acc[i][1], acc[i][2], acc[i][3]);
    *(float4*)(part + ((size_t)dsp * NB + r) * NK + kb) = v;
  }
}

// One wave per batch row: reduce DSPLIT partials, +log w, NaN fix,
// log-sum-exp with the reference's per-term +1e-8, exp.
__global__ __launch_bounds__(256) void k_final(
    const float* __restrict__ ws, float* __restrict__ out) {
  const float* lw   = ws + 3 * KD;
  const float* part = ws + 3 * KD + NK;
  int lane = threadIdx.x & 63;
  int wv   = threadIdx.x >> 6;
  int b = blockIdx.x * 4 + wv;

  float dep[2];
#pragma unroll
  for (int t = 0; t < 2; t++) {
    int k = lane + t * 64;
    float s = 0.f;
#pragma unroll
    for (int sp = 0; sp < DSPLIT; sp++)
      s += part[((size_t)sp * NB + b) * NK + k];
    s += lw[k];
    if (isnan(s)) s = 0.f;
    dep[t] = s;
  }
  float mx = fmaxf(dep[0], dep[1]);
#pragma unroll
  for (int off = 32; off; off >>= 1) mx = fmaxf(mx, __shfl_xor(mx, off));
  // reference: sum_k (exp(dep-max) + 1e-8)  -> 2 terms per lane
  float sum = expf(dep[0] - mx) + expf(dep[1] - mx) + 2e-8f;
#pragma unroll
  for (int off = 32; off; off >>= 1) sum += __shfl_xor(sum, off);
  float lse = logf(sum) + mx;
  out[(size_t)b * NK + lane]      = expf(dep[0] - lse);
  out[(size_t)b * NK + lane + 64] = expf(dep[1] - lse);
}

extern "C" void kernel_launch(void* const* d_in, const int* in_sizes, int n_in,
                              void* d_out, int out_size, void* d_ws, size_t ws_size,
                              hipStream_t stream) {
  const float* data = (const float*)d_in[0];
  const float* mask = (const float*)d_in[1];
  const float* wts  = (const float*)d_in[2];
  const float* mu   = (const float*)d_in[3];
  const float* cov  = (const float*)d_in[4];
  float* ws  = (float*)d_ws;
  float* out = (float*)d_out;

  k_tables<<<(KD + 255) / 256, 256, 0, stream>>>(wts, mu, cov, ws);
  k_main<<<(NB / BM) * DSPLIT, 256, 0, stream>>>(data, mask, ws);
  k_final<<<NB / 4, 256, 0, stream>>>(ws, out);
}